// Round 14
// baseline (121.514 us; speedup 1.0000x reference)
//
#include <hip/hip_runtime.h>
#include <stdint.h>

#define B_   32
#define DIM_ 16
#define H_   128
#define DM_  256
#define NH_  8
#define WP_  32     // DM/NH
#define C3_  384    // 3*NH*DIM

typedef short bf16x8 __attribute__((ext_vector_type(8)));
typedef float f32x4  __attribute__((ext_vector_type(4)));

__device__ __forceinline__ unsigned short f2bfu(float v) {
    unsigned int x = __float_as_uint(v);
    x += 0x7fffu + ((x >> 16) & 1u);   // RNE
    return (unsigned short)(x >> 16);
}
__device__ __forceinline__ unsigned cvtpk(float lo, float hi) {
    unsigned r;
    asm("v_cvt_pk_bf16_f32 %0, %1, %2" : "=v"(r) : "v"(lo), "v"(hi));
    return r;
}
// async global->LDS, 16B per lane; lds dest = wave-uniform base + lane*16
__device__ __forceinline__ void gl_lds16(const void* g, void* l) {
    __builtin_amdgcn_global_load_lds(
        (const __attribute__((address_space(1))) unsigned int*)g,
        (__attribute__((address_space(3))) unsigned int*)l, 16, 0, 0);
}

// ============================================================================
// Kernel 1 (v11): implicit-GEMM MFMA conv, 4x smaller tile for residency.
// v10 post-mortem: MFMA formulation also ~59us, but 77.8KB LDS -> 2 blk/CU
// (16 waves) and 32-iter serial N-loop. v11: per (b,g,h-eighth) block:
// 22 x-rows hi/lo (22.5KB) + W_eff (6KB) = 28.7KB -> 5 blk/CU (~20+ waves),
// grid 4096, 8 N-iters/wave. Formulas identical to v10 (verified, absmax ok).
// Rows staged 0..21 cover rl = h_l + t <= 15+5+ (t=5 zero-pad reads must hit
// staged-finite data -> no NaN*0).
// Grid decode: hq = bid&7, g = (bid>>3)&15, b = bid>>7. 256 thr.
// ============================================================================
__global__ __launch_bounds__(256) void conv_kernel(
    const float* __restrict__ x, const float* __restrict__ w1,
    const float* __restrict__ w2, unsigned short* __restrict__ y2)
{
    __shared__ __align__(16) unsigned char sm[28672];  // Xhi@0 Xlo@11264 W@22528

    const int bid = blockIdx.x;
    const int hq = bid & 7;
    const int g  = (bid >> 3) & 15;
    const int b  = bid >> 7;
    const int h0 = hq * 16;
    const int tid = threadIdx.x;

    const float* xg = x + ((size_t)(b * DIM_ + g)) * H_ * DM_;

    // ---- stage X as hi/lo bf16, rows h0-2 .. h0+19 (22 rows x 32 chunks) ----
    for (int i = tid; i < 704; i += 256) {
        const int row = i >> 5, c = i & 31;
        const int hg = h0 + row - 2;
        float4 fa = make_float4(0.f, 0.f, 0.f, 0.f);
        float4 fb = make_float4(0.f, 0.f, 0.f, 0.f);
        if (hg >= 0 && hg < H_) {
            const float4* p = (const float4*)(xg + (size_t)hg * DM_ + c * 8);
            fa = p[0]; fb = p[1];
        }
        unsigned h0p = cvtpk(fa.x, fa.y), h1p = cvtpk(fa.z, fa.w);
        unsigned h2p = cvtpk(fb.x, fb.y), h3p = cvtpk(fb.z, fb.w);
        unsigned l0 = cvtpk(fa.x - __uint_as_float(h0p << 16),
                            fa.y - __uint_as_float(h0p & 0xffff0000u));
        unsigned l1 = cvtpk(fa.z - __uint_as_float(h1p << 16),
                            fa.w - __uint_as_float(h1p & 0xffff0000u));
        unsigned l2 = cvtpk(fb.x - __uint_as_float(h2p << 16),
                            fb.y - __uint_as_float(h2p & 0xffff0000u));
        unsigned l3 = cvtpk(fb.z - __uint_as_float(h3p << 16),
                            fb.w - __uint_as_float(h3p & 0xffff0000u));
        const int off = row * 512 + ((c ^ (row & 7)) << 4);
        *(uint4*)(sm + off)         = make_uint4(h0p, h1p, h2p, h3p);
        *(uint4*)(sm + 11264 + off) = make_uint4(l0, l1, l2, l3);
    }

    // ---- stage W_eff[32][96] bf16 (same value both k-halves; 0 pads) ----
    unsigned short* smW = (unsigned short*)(sm + 22528);
    for (int i = tid; i < 3072; i += 256) {
        const int o = i / 96, k = i % 96;
        const int kk = (k >= 48) ? k - 48 : k;
        const int t = kk >> 3, j = kk & 7;
        float w = 0.f;
        if (o < 24 && t < 5)
            w = w1[(g * 24 + o) * 5 + t] * w2[(g * 24 + o) * 8 + j];
        smW[o * 96 + k] = f2bfu(w);
    }
    __syncthreads();

    const int l = tid & 63, wv = tid >> 6, lm = l & 15, lk = l >> 4;

    // A-frags (W) to registers: aw[mt][kf]
    bf16x8 aw[2][3];
    #pragma unroll
    for (int mt = 0; mt < 2; ++mt)
        #pragma unroll
        for (int kf = 0; kf < 3; ++kf)
            aw[mt][kf] = *(const bf16x8*)((const unsigned char*)smW
                          + (mt * 16 + lm) * 192 + kf * 64 + lk * 16);

    // per-lane B-read params: k0 = kf*32 + lk*8 -> part, t
    int tpar[3], ppar[3];
    #pragma unroll
    for (int kf = 0; kf < 3; ++kf) {
        const int k0 = kf * 32 + lk * 8;
        const int part = (k0 >= 48) ? 1 : 0;
        tpar[kf] = (k0 - part * 48) >> 3;
        ppar[kf] = part * 11264;
    }

    unsigned short* zb = y2 + (size_t)(b * C3_ + g * 24) * 4096;

    #pragma unroll
    for (int i = 0; i < 8; ++i) {
        const int nt = wv * 8 + i;
        const int h_l = nt >> 1, wpb = (nt & 1) << 4;
        const int wp = wpb + lm;
        f32x4 acc0 = 0, acc1 = 0;
        #pragma unroll
        for (int kf = 0; kf < 3; ++kf) {
            const int rl = h_l + tpar[kf];
            bf16x8 xb = *(const bf16x8*)(sm + ppar[kf] + rl * 512
                          + ((wp ^ (rl & 7)) << 4));
            acc0 = __builtin_amdgcn_mfma_f32_16x16x32_bf16(xb, aw[0][kf], acc0, 0, 0, 0);
            acc1 = __builtin_amdgcn_mfma_f32_16x16x32_bf16(xb, aw[1][kf], acc1, 0, 0, 0);
        }
        const int h = h0 + h_l;
        const int wpst = wpb + lk * 4;
        *(uint2*)(zb + (size_t)lm * 4096 + h * 32 + wpst) =
            make_uint2(cvtpk(acc0[0], acc0[1]), cvtpk(acc0[2], acc0[3]));
        if (lm < 8)
            *(uint2*)(zb + (size_t)(16 + lm) * 4096 + h * 32 + wpst) =
                make_uint2(cvtpk(acc1[0], acc1[1]), cvtpk(acc1[2], acc1[3]));
    }
}

// ============================================================================
// Kernel 2: MFMA attention per (b, ch). Unchanged (known-good;
// Q/K/V all read from [o][h][wp]; V transposed into Vt LDS via scalar scatter).
// ============================================================================
__global__ __launch_bounds__(256) void attn_kernel(
    const unsigned short* __restrict__ y2, unsigned short* __restrict__ z)
{
    __shared__ __align__(16) unsigned char sm[40960];

    const int tid = threadIdx.x;
    const int ch = blockIdx.x & 127, b = blockIdx.x >> 7;
    const size_t base = ((size_t)(b * C3_ + ch)) * 4096;
    const uint4* qg = (const uint4*)(y2 + base);
    const uint4* kg = (const uint4*)(y2 + base + 128 * 4096);
    const uint4* vg = (const uint4*)(y2 + base + 256 * 4096);

    #pragma unroll
    for (int r = 0; r < 2; ++r) {
        const int ci  = tid + r * 256;
        const int row = ci >> 2;
        const int c   = ci & 3;
        const int cx  = c ^ ((row >> 1) & 3);
        *(uint4*)(sm + row * 64 + cx * 16)        = qg[ci];
        *(uint4*)(sm + 8192 + row * 64 + cx * 16) = kg[ci];
        uint4 v = vg[ci];
        unsigned short vs[8];
        vs[0] = (unsigned short)(v.x & 0xffffu); vs[1] = (unsigned short)(v.x >> 16);
        vs[2] = (unsigned short)(v.y & 0xffffu); vs[3] = (unsigned short)(v.y >> 16);
        vs[4] = (unsigned short)(v.z & 0xffffu); vs[5] = (unsigned short)(v.z >> 16);
        vs[6] = (unsigned short)(v.w & 0xffffu); vs[7] = (unsigned short)(v.w >> 16);
        const int d0 = c * 8;
        #pragma unroll
        for (int j = 0; j < 8; ++j) {
            const int d = d0 + j;
            *(unsigned short*)(sm + 32768 + d * 256 + ((row * 2) ^ ((d & 7) << 4))) = vs[j];
        }
    }
    __syncthreads();

    const int l  = tid & 63, wv = tid >> 6;
    const int lm = l & 15,  lk = l >> 4;

    bf16x8 qf[2];
    #pragma unroll
    for (int t = 0; t < 2; ++t) {
        const int q = (wv * 2 + t) * 16 + lm;
        qf[t] = *(const bf16x8*)(sm + q * 64 + ((lk ^ ((q >> 1) & 3)) << 4));
    }
    f32x4 acc[8][2];
    #pragma unroll
    for (int rt = 0; rt < 8; ++rt) {
        acc[rt][0] = 0; acc[rt][1] = 0;
    }
    #pragma unroll
    for (int rt = 0; rt < 8; ++rt) {
        const int kr = rt * 16 + lm;
        bf16x8 kf = *(const bf16x8*)(sm + 8192 + kr * 64 + ((lk ^ ((kr >> 1) & 3)) << 4));
        acc[rt][0] = __builtin_amdgcn_mfma_f32_16x16x32_bf16(kf, qf[0], acc[rt][0], 0, 0, 0);
        acc[rt][1] = __builtin_amdgcn_mfma_f32_16x16x32_bf16(kf, qf[1], acc[rt][1], 0, 0, 0);
    }

    const float Cc = 0.17677669529663687f * 1.4426950408889634f;
    float inv[2];
    #pragma unroll
    for (int t = 0; t < 2; ++t) {
        float m = acc[0][t][0];
        #pragma unroll
        for (int rt = 0; rt < 8; ++rt)
            #pragma unroll
            for (int rg = 0; rg < 4; ++rg) m = fmaxf(m, acc[rt][t][rg]);
        m = fmaxf(m, __shfl_xor(m, 16));
        m = fmaxf(m, __shfl_xor(m, 32));
        float s = 0.f;
        #pragma unroll
        for (int rt = 0; rt < 8; ++rt)
            #pragma unroll
            for (int rg = 0; rg < 4; ++rg) {
                float p = exp2f((acc[rt][t][rg] - m) * Cc);
                acc[rt][t][rg] = p; s += p;
            }
        s += __shfl_xor(s, 16);
        s += __shfl_xor(s, 32);
        inv[t] = 1.0f / s;
    }

    __syncthreads();

    #pragma unroll
    for (int t = 0; t < 2; ++t) {
        const int q = (wv * 2 + t) * 16 + lm;
        #pragma unroll
        for (int rt = 0; rt < 8; ++rt) {
            unsigned u0 = cvtpk(acc[rt][t][0] * inv[t], acc[rt][t][1] * inv[t]);
            unsigned u1 = cvtpk(acc[rt][t][2] * inv[t], acc[rt][t][3] * inv[t]);
            const int kb = rt * 32 + lk * 8;
            *(uint2*)(sm + q * 256 + (kb ^ ((q & 7) << 4))) = make_uint2(u0, u1);
        }
    }
    __syncthreads();

    f32x4 o[2][2];
    o[0][0] = 0; o[0][1] = 0; o[1][0] = 0; o[1][1] = 0;
    #pragma unroll
    for (int kc = 0; kc < 4; ++kc) {
        const int cb = kc * 64 + lk * 16;
        bf16x8 av[2], bp[2];
        #pragma unroll
        for (int dt = 0; dt < 2; ++dt) {
            const int d = dt * 16 + lm;
            av[dt] = *(const bf16x8*)(sm + 32768 + d * 256 + (cb ^ ((d & 7) << 4)));
        }
        #pragma unroll
        for (int t = 0; t < 2; ++t) {
            const int q = (wv * 2 + t) * 16 + lm;
            bp[t] = *(const bf16x8*)(sm + q * 256 + (cb ^ ((q & 7) << 4)));
        }
        #pragma unroll
        for (int dt = 0; dt < 2; ++dt)
            #pragma unroll
            for (int t = 0; t < 2; ++t)
                o[dt][t] = __builtin_amdgcn_mfma_f32_16x16x32_bf16(av[dt], bp[t], o[dt][t], 0, 0, 0);
    }

    const int dd = ch >> 3, nn = ch & 7;
    unsigned short* zb = z + ((size_t)(b * DIM_ + dd)) * (H_ * DM_);
    #pragma unroll
    for (int dt = 0; dt < 2; ++dt)
        #pragma unroll
        for (int t = 0; t < 2; ++t) {
            const int q  = (wv * 2 + t) * 16 + lm;
            const int d0 = dt * 16 + lk * 4;
            unsigned u0 = cvtpk(o[dt][t][0], o[dt][t][1]);
            unsigned u1 = cvtpk(o[dt][t][2], o[dt][t][3]);
            *(uint2*)(zb + (size_t)q * DM_ + nn * 32 + d0) = make_uint2(u0, u1);
        }
}

// ============================================================================
// Kernel 3: W -> bf16 hi/lo split. Unchanged.
// ============================================================================
__global__ __launch_bounds__(256) void prep_w(
    const float* __restrict__ w, unsigned short* __restrict__ wh,
    unsigned short* __restrict__ wl)
{
    const int i = blockIdx.x * 1024 + threadIdx.x * 4;
    float4 v = *(const float4*)(w + i);
    float vv[4] = { v.x, v.y, v.z, v.w };
    unsigned short h[4], lo[4];
    #pragma unroll
    for (int j = 0; j < 4; ++j) {
        h[j] = f2bfu(vv[j]);
        float hf = __uint_as_float(((unsigned)h[j]) << 16);
        lo[j] = f2bfu(vv[j] - hf);
    }
    *(uint2*)(wh + i) = make_uint2((unsigned)h[0] | ((unsigned)h[1] << 16),
                                   (unsigned)h[2] | ((unsigned)h[3] << 16));
    *(uint2*)(wl + i) = make_uint2((unsigned)lo[0] | ((unsigned)lo[1] << 16),
                                   (unsigned)lo[2] | ((unsigned)lo[3] << 16));
}

// ============================================================================
// Kernel 4 (v2): MFMA out-projection, swapped operands + float4 epilogue.
// Unchanged (known-good).
// ============================================================================
__global__ __launch_bounds__(256) void proj_kernel(
    const unsigned short* __restrict__ zz, const unsigned short* __restrict__ wh,
    const unsigned short* __restrict__ wl, const float* __restrict__ bias,
    float* __restrict__ out)
{
    __shared__ __align__(16) unsigned char sm[65536];   // 2 bufs x 32KB
    const int tid = threadIdx.x;
    const int l = tid & 63, wv = tid >> 6, lm = l & 15, lk = l >> 4;
    const unsigned short* zs = zz + (size_t)blockIdx.x * 32768;

    const int g_off = (tid >> 2) * 256 + (tid & 3) * 8;
    const int lds_wv = wv * 1024;

    const int arow0 = wv * 32 + lm;

    f32x4 acc[2][16];
    #pragma unroll
    for (int t = 0; t < 2; ++t)
        #pragma unroll
        for (int nt = 0; nt < 16; ++nt) acc[t][nt] = 0;

    bf16x8 areg[2][2];

    #pragma unroll
    for (int i = 0; i < 8; ++i) {
        const unsigned short* g = (i < 4 ? wh : wl) + g_off + (i & 3) * 16384;
        gl_lds16(g, sm + i * 4096 + lds_wv);
    }
    #pragma unroll
    for (int t = 0; t < 2; ++t)
        areg[0][t] = *(const bf16x8*)(zs + (size_t)(arow0 + t * 16) * 256 + lk * 8);

    __syncthreads();

    #pragma unroll
    for (int kc = 0; kc < 8; ++kc) {
        const int buf = kc & 1;
        if (kc < 7) {
            #pragma unroll
            for (int i = 0; i < 8; ++i) {
                const unsigned short* g = (i < 4 ? wh : wl) + g_off + (i & 3) * 16384 + (kc + 1) * 32;
                gl_lds16(g, sm + (buf ^ 1) * 32768 + i * 4096 + lds_wv);
            }
            #pragma unroll
            for (int t = 0; t < 2; ++t)
                areg[buf ^ 1][t] = *(const bf16x8*)(zs + (size_t)(arow0 + t * 16) * 256 + (kc + 1) * 32 + lk * 8);
        }
        #pragma unroll
        for (int ph = 0; ph < 2; ++ph)
            #pragma unroll
            for (int nt = 0; nt < 16; ++nt) {
                bf16x8 bf = *(const bf16x8*)(sm + buf * 32768 + ph * 16384 + nt * 1024 + lm * 64 + lk * 16);
                acc[0][nt] = __builtin_amdgcn_mfma_f32_16x16x32_bf16(bf, areg[buf][0], acc[0][nt], 0, 0, 0);
                acc[1][nt] = __builtin_amdgcn_mfma_f32_16x16x32_bf16(bf, areg[buf][1], acc[1][nt], 0, 0, 0);
            }
        __syncthreads();
    }

    float* ob = out + (size_t)blockIdx.x * 32768;
    #pragma unroll
    for (int t = 0; t < 2; ++t) {
        const int row = wv * 32 + t * 16 + lm;
        #pragma unroll
        for (int nt = 0; nt < 16; ++nt) {
            const int col = nt * 16 + lk * 4;
            const float4 bv = *(const float4*)(bias + col);
            float4 vv = make_float4(acc[t][nt][0] + bv.x, acc[t][nt][1] + bv.y,
                                    acc[t][nt][2] + bv.z, acc[t][nt][3] + bv.w);
            *(float4*)&ob[(size_t)row * 256 + col] = vv;
        }
    }
}

// ============================================================================
extern "C" void kernel_launch(void* const* d_in, const int* in_sizes, int n_in,
                              void* d_out, int out_size, void* d_ws, size_t ws_size,
                              hipStream_t stream)
{
    const float* x  = (const float*)d_in[0];
    const float* w1 = (const float*)d_in[1];
    const float* w2 = (const float*)d_in[2];
    const float* wo = (const float*)d_in[3];
    const float* wb = (const float*)d_in[4];
    float* out = (float*)d_out;

    unsigned short* y2 = (unsigned short*)d_ws;                    // 100,663,296 B
    unsigned short* zz = y2 + (size_t)B_ * C3_ * H_ * WP_;         // + 33,554,432 B
    unsigned short* wh = y2;                                       // overlays dead y2 (after attn)
    unsigned short* wl = y2 + 65536;

    conv_kernel<<<dim3(4096), dim3(256), 0, stream>>>(x, w1, w2, y2);
    attn_kernel<<<dim3(4096), dim3(256), 0, stream>>>(y2, zz);
    prep_w<<<dim3(64), dim3(256), 0, stream>>>(wo, wh, wl);
    proj_kernel<<<dim3(512), dim3(256), 0, stream>>>(zz, wh, wl, wb, out);
}

// Round 15
// 117.879 us; speedup vs baseline: 1.0308x; 1.0308x over previous
//
#include <hip/hip_runtime.h>
#include <stdint.h>

#define B_   32
#define DIM_ 16
#define H_   128
#define DM_  256
#define NH_  8
#define WP_  32     // DM/NH
#define C3_  384    // 3*NH*DIM

typedef short bf16x8 __attribute__((ext_vector_type(8)));
typedef float f32x4  __attribute__((ext_vector_type(4)));

__device__ __forceinline__ unsigned short f2bfu(float v) {
    unsigned int x = __float_as_uint(v);
    x += 0x7fffu + ((x >> 16) & 1u);   // RNE
    return (unsigned short)(x >> 16);
}
__device__ __forceinline__ unsigned cvtpk(float lo, float hi) {
    unsigned r;
    asm("v_cvt_pk_bf16_f32 %0, %1, %2" : "=v"(r) : "v"(lo), "v"(hi));
    return r;
}
// async global->LDS, 16B per lane; lds dest = wave-uniform base + lane*16
__device__ __forceinline__ void gl_lds16(const void* g, void* l) {
    __builtin_amdgcn_global_load_lds(
        (const __attribute__((address_space(1))) unsigned int*)g,
        (__attribute__((address_space(3))) unsigned int*)l, 16, 0, 0);
}
// two HW-transpose LDS reads (4 bf16 each, +512B for upper d-quad), one wait
__device__ __forceinline__ void tr2(const void* p, uint2& r0, uint2& r1) {
    const __attribute__((address_space(3))) unsigned char* lp =
        (const __attribute__((address_space(3))) unsigned char*)p;
    asm volatile("s_waitcnt lgkmcnt(0)\n\t"
                 "ds_read_b64_tr_b16 %0, %2\n\t"
                 "ds_read_b64_tr_b16 %1, %2 offset:512\n\t"
                 "s_waitcnt lgkmcnt(0)"
                 : "=v"(r0), "=v"(r1) : "v"(lp) : "memory");
}
__device__ __forceinline__ bf16x8 mk8(uint2 r0, uint2 r1) {
    union { uint4 u; bf16x8 v; } c;
    c.u = make_uint4(r0.x, r0.y, r1.x, r1.y);
    return c.v;
}

// ============================================================================
// Kernel 1 (v12): v9 pure-store conv with FULL-CACHE-LINE wave stores.
// Identical compute/weights/layout to v9 ([o][wp][h], round-12-verified);
// only the lane->(hl,wp) map changes: hl = tid&7, wp = tid>>3. Each wave's
// uint4 store now covers 8 wp x (8 hl x 16B) = 8 full 128B lines (was 32
// scattered 32B txns). x-read txn count unchanged (8 rows x 256B runs).
// Tests the store-transaction-rate hypothesis for the ~55us conv wall.
// Grid: 32 b * 16 g * 2 ht = 1024 blocks, 256 thr.
// ============================================================================
__global__ __launch_bounds__(256) void conv_kernel(
    const float* __restrict__ x, const float* __restrict__ w1,
    const float* __restrict__ w2, unsigned short* __restrict__ y2)
{
    __shared__ float wlds[24 * 16];   // [oc][0..4]=w1, [5..12]=w2, rest pad

    const int bid = blockIdx.x;
    const int ht = bid & 1;
    const int g  = (bid >> 1) & 15;
    const int b  = bid >> 5;
    const int tid = threadIdx.x;
    const int hl = tid & 7;           // h-oct within half (minor -> contiguity)
    const int wp = tid >> 3;          // 0..31
    const int h0 = ht * 64 + hl * 8;  // first output h of this thread

    for (int i = tid; i < 384; i += 256) {
        const int oc = i >> 4, ix = i & 15;
        const int o = g * 24 + oc;
        float v = 0.f;
        if (ix < 5)       v = w1[o * 5 + ix];
        else if (ix < 13) v = w2[o * 8 + (ix - 5)];
        wlds[i] = v;
    }

    const float* xbase = x + ((size_t)(b * DIM_ + g) * H_) * DM_ + wp * 8;

    float xr[12][8];
    #pragma unroll
    for (int r = 0; r < 12; ++r) {
        const int hr = h0 - 2 + r;
        if (hr >= 0 && hr < H_) {
            const float4* p = (const float4*)(xbase + (size_t)hr * DM_);
            float4 a = p[0], c = p[1];
            xr[r][0] = a.x; xr[r][1] = a.y; xr[r][2] = a.z; xr[r][3] = a.w;
            xr[r][4] = c.x; xr[r][5] = c.y; xr[r][6] = c.z; xr[r][7] = c.w;
        } else {
            #pragma unroll
            for (int j = 0; j < 8; ++j) xr[r][j] = 0.f;
        }
    }
    __syncthreads();

    // store base: [o][wp][h], o = g*24 + oc
    unsigned short* yb = y2 + ((size_t)(b * C3_ + g * 24) * 32 + wp) * 128 + h0;

    for (int oc = 0; oc < 24; ++oc) {
        const float* wo_ = &wlds[oc * 16];
        float w1r[5], w2r[8];
        {
            float4 a = *(const float4*)(wo_);       // w1[0..3]
            float4 c = *(const float4*)(wo_ + 4);   // w1[4], w2[0..2]
            float4 d = *(const float4*)(wo_ + 8);   // w2[3..6]
            w1r[0] = a.x; w1r[1] = a.y; w1r[2] = a.z; w1r[3] = a.w;
            w1r[4] = c.x;
            w2r[0] = c.y; w2r[1] = c.z; w2r[2] = c.w;
            w2r[3] = d.x; w2r[4] = d.y; w2r[5] = d.z; w2r[6] = d.w;
            w2r[7] = wo_[12];
        }

        float u[12];
        #pragma unroll
        for (int r = 0; r < 12; ++r) {
            float s = w2r[0] * xr[r][0];
            #pragma unroll
            for (int j = 1; j < 8; ++j) s = fmaf(w2r[j], xr[r][j], s);
            u[r] = s;
        }

        float ys[8];
        #pragma unroll
        for (int hh = 0; hh < 8; ++hh) {
            float y = w1r[0] * u[hh];
            #pragma unroll
            for (int t = 1; t < 5; ++t) y = fmaf(w1r[t], u[hh + t], y);
            ys[hh] = y;
        }
        uint4 pk;
        pk.x = cvtpk(ys[0], ys[1]); pk.y = cvtpk(ys[2], ys[3]);
        pk.z = cvtpk(ys[4], ys[5]); pk.w = cvtpk(ys[6], ys[7]);
        *(uint4*)(yb + (size_t)oc * 4096) = pk;
    }
}

// ============================================================================
// Kernel 2 (v3): MFMA attention per (b, ch). Round-12 version (verified for
// the [o][d][h] layout): Q/K staged into tr-tiles, fragments via
// ds_read_b64_tr_b16 (tr d-permutation cancels between Q and K);
// V staged directly to Vt rows ([d][k=h] natural in this layout).
// ============================================================================
__global__ __launch_bounds__(256) void attn_kernel(
    const unsigned short* __restrict__ y2, unsigned short* __restrict__ z)
{
    __shared__ __align__(16) unsigned char sm[40960];

    const int tid = threadIdx.x;
    const int ch = blockIdx.x & 127, b = blockIdx.x >> 7;
    const size_t base = ((size_t)(b * C3_ + ch)) * 4096;
    const uint4* qg = (const uint4*)(y2 + base);
    const uint4* kg = (const uint4*)(y2 + base + 128 * 4096);
    const uint4* vg = (const uint4*)(y2 + base + 256 * 4096);

    // ---- stage: Q tiles @0, K tiles @8192 (tr-tile layout), Vt @32768 ----
    #pragma unroll
    for (int r = 0; r < 2; ++r) {
        const int ci  = tid + r * 256;   // 0..511 uint4 chunks: [d=ci>>4][hc=ci&15]
        const int vd  = ci >> 4;         // 0..31
        const int vhc = ci & 15;         // 16B chunk along h (8 h values)
        const int toff = (vhc >> 1) * 1024 +
            ((((vhc & 1) * 8) + 16 * (vd & 3) + 256 * ((vd >> 2) & 1) + 64 * (vd >> 3)) << 1);
        *(uint4*)(sm + toff)        = qg[ci];
        *(uint4*)(sm + 8192 + toff) = kg[ci];
        *(uint4*)(sm + 32768 + vd * 256 + ((vhc * 16) ^ ((vd & 7) << 4))) = vg[ci];
    }
    __syncthreads();

    const int l  = tid & 63, wv = tid >> 6;
    const int lm = l & 15,  lk = l >> 4;
    const unsigned rdo = ((l & 15) + 64 * (l >> 4)) * 2;   // tr-read offset

    // ---- QK^T: S^T[k][q], wave wv owns q columns 32wv..32wv+31 ----
    bf16x8 qf[2];
    #pragma unroll
    for (int t = 0; t < 2; ++t) {
        uint2 r0, r1;
        tr2(sm + (wv * 2 + t) * 1024 + rdo, r0, r1);
        qf[t] = mk8(r0, r1);
    }
    f32x4 acc[8][2];
    #pragma unroll
    for (int rt = 0; rt < 8; ++rt) {
        acc[rt][0] = 0; acc[rt][1] = 0;
    }
    #pragma unroll
    for (int rt = 0; rt < 8; ++rt) {
        uint2 r0, r1;
        tr2(sm + 8192 + rt * 1024 + rdo, r0, r1);
        bf16x8 kf = mk8(r0, r1);
        acc[rt][0] = __builtin_amdgcn_mfma_f32_16x16x32_bf16(kf, qf[0], acc[rt][0], 0, 0, 0);
        acc[rt][1] = __builtin_amdgcn_mfma_f32_16x16x32_bf16(kf, qf[1], acc[rt][1], 0, 0, 0);
    }

    const float Cc = 0.17677669529663687f * 1.4426950408889634f;
    float inv[2];
    #pragma unroll
    for (int t = 0; t < 2; ++t) {
        float m = acc[0][t][0];
        #pragma unroll
        for (int rt = 0; rt < 8; ++rt)
            #pragma unroll
            for (int rg = 0; rg < 4; ++rg) m = fmaxf(m, acc[rt][t][rg]);
        m = fmaxf(m, __shfl_xor(m, 16));
        m = fmaxf(m, __shfl_xor(m, 32));
        float s = 0.f;
        #pragma unroll
        for (int rt = 0; rt < 8; ++rt)
            #pragma unroll
            for (int rg = 0; rg < 4; ++rg) {
                float p = exp2f((acc[rt][t][rg] - m) * Cc);
                acc[rt][t][rg] = p; s += p;
            }
        s += __shfl_xor(s, 16);
        s += __shfl_xor(s, 32);
        inv[t] = 1.0f / s;
    }

    __syncthreads();   // Q/K reads done -> safe to overlay P

    #pragma unroll
    for (int t = 0; t < 2; ++t) {
        const int q = (wv * 2 + t) * 16 + lm;
        #pragma unroll
        for (int rt = 0; rt < 8; ++rt) {
            unsigned u0 = cvtpk(acc[rt][t][0] * inv[t], acc[rt][t][1] * inv[t]);
            unsigned u1 = cvtpk(acc[rt][t][2] * inv[t], acc[rt][t][3] * inv[t]);
            const int kb = rt * 32 + lk * 8;
            *(uint2*)(sm + q * 256 + (kb ^ ((q & 7) << 4))) = make_uint2(u0, u1);
        }
    }
    __syncthreads();

    f32x4 o[2][2];
    o[0][0] = 0; o[0][1] = 0; o[1][0] = 0; o[1][1] = 0;
    #pragma unroll
    for (int kc = 0; kc < 4; ++kc) {
        const int cb = kc * 64 + lk * 16;
        bf16x8 av[2], bp[2];
        #pragma unroll
        for (int dt = 0; dt < 2; ++dt) {
            const int d = dt * 16 + lm;
            av[dt] = *(const bf16x8*)(sm + 32768 + d * 256 + (cb ^ ((d & 7) << 4)));
        }
        #pragma unroll
        for (int t = 0; t < 2; ++t) {
            const int q = (wv * 2 + t) * 16 + lm;
            bp[t] = *(const bf16x8*)(sm + q * 256 + (cb ^ ((q & 7) << 4)));
        }
        #pragma unroll
        for (int dt = 0; dt < 2; ++dt)
            #pragma unroll
            for (int t = 0; t < 2; ++t)
                o[dt][t] = __builtin_amdgcn_mfma_f32_16x16x32_bf16(av[dt], bp[t], o[dt][t], 0, 0, 0);
    }

    const int dd = ch >> 3, nn = ch & 7;
    unsigned short* zb = z + ((size_t)(b * DIM_ + dd)) * (H_ * DM_);
    #pragma unroll
    for (int dt = 0; dt < 2; ++dt)
        #pragma unroll
        for (int t = 0; t < 2; ++t) {
            const int q  = (wv * 2 + t) * 16 + lm;
            const int d0 = dt * 16 + lk * 4;
            unsigned u0 = cvtpk(o[dt][t][0], o[dt][t][1]);
            unsigned u1 = cvtpk(o[dt][t][2], o[dt][t][3]);
            *(uint2*)(zb + (size_t)q * DM_ + nn * 32 + d0) = make_uint2(u0, u1);
        }
}

// ============================================================================
// Kernel 3: W -> bf16 hi/lo split. Unchanged.
// ============================================================================
__global__ __launch_bounds__(256) void prep_w(
    const float* __restrict__ w, unsigned short* __restrict__ wh,
    unsigned short* __restrict__ wl)
{
    const int i = blockIdx.x * 1024 + threadIdx.x * 4;
    float4 v = *(const float4*)(w + i);
    float vv[4] = { v.x, v.y, v.z, v.w };
    unsigned short h[4], lo[4];
    #pragma unroll
    for (int j = 0; j < 4; ++j) {
        h[j] = f2bfu(vv[j]);
        float hf = __uint_as_float(((unsigned)h[j]) << 16);
        lo[j] = f2bfu(vv[j] - hf);
    }
    *(uint2*)(wh + i) = make_uint2((unsigned)h[0] | ((unsigned)h[1] << 16),
                                   (unsigned)h[2] | ((unsigned)h[3] << 16));
    *(uint2*)(wl + i) = make_uint2((unsigned)lo[0] | ((unsigned)lo[1] << 16),
                                   (unsigned)lo[2] | ((unsigned)lo[3] << 16));
}

// ============================================================================
// Kernel 4 (v2): MFMA out-projection, swapped operands + float4 epilogue.
// Unchanged (known-good).
// ============================================================================
__global__ __launch_bounds__(256) void proj_kernel(
    const unsigned short* __restrict__ zz, const unsigned short* __restrict__ wh,
    const unsigned short* __restrict__ wl, const float* __restrict__ bias,
    float* __restrict__ out)
{
    __shared__ __align__(16) unsigned char sm[65536];   // 2 bufs x 32KB
    const int tid = threadIdx.x;
    const int l = tid & 63, wv = tid >> 6, lm = l & 15, lk = l >> 4;
    const unsigned short* zs = zz + (size_t)blockIdx.x * 32768;

    const int g_off = (tid >> 2) * 256 + (tid & 3) * 8;
    const int lds_wv = wv * 1024;

    const int arow0 = wv * 32 + lm;

    f32x4 acc[2][16];
    #pragma unroll
    for (int t = 0; t < 2; ++t)
        #pragma unroll
        for (int nt = 0; nt < 16; ++nt) acc[t][nt] = 0;

    bf16x8 areg[2][2];

    #pragma unroll
    for (int i = 0; i < 8; ++i) {
        const unsigned short* g = (i < 4 ? wh : wl) + g_off + (i & 3) * 16384;
        gl_lds16(g, sm + i * 4096 + lds_wv);
    }
    #pragma unroll
    for (int t = 0; t < 2; ++t)
        areg[0][t] = *(const bf16x8*)(zs + (size_t)(arow0 + t * 16) * 256 + lk * 8);

    __syncthreads();

    #pragma unroll
    for (int kc = 0; kc < 8; ++kc) {
        const int buf = kc & 1;
        if (kc < 7) {
            #pragma unroll
            for (int i = 0; i < 8; ++i) {
                const unsigned short* g = (i < 4 ? wh : wl) + g_off + (i & 3) * 16384 + (kc + 1) * 32;
                gl_lds16(g, sm + (buf ^ 1) * 32768 + i * 4096 + lds_wv);
            }
            #pragma unroll
            for (int t = 0; t < 2; ++t)
                areg[buf ^ 1][t] = *(const bf16x8*)(zs + (size_t)(arow0 + t * 16) * 256 + (kc + 1) * 32 + lk * 8);
        }
        #pragma unroll
        for (int ph = 0; ph < 2; ++ph)
            #pragma unroll
            for (int nt = 0; nt < 16; ++nt) {
                bf16x8 bf = *(const bf16x8*)(sm + buf * 32768 + ph * 16384 + nt * 1024 + lm * 64 + lk * 16);
                acc[0][nt] = __builtin_amdgcn_mfma_f32_16x16x32_bf16(bf, areg[buf][0], acc[0][nt], 0, 0, 0);
                acc[1][nt] = __builtin_amdgcn_mfma_f32_16x16x32_bf16(bf, areg[buf][1], acc[1][nt], 0, 0, 0);
            }
        __syncthreads();
    }

    float* ob = out + (size_t)blockIdx.x * 32768;
    #pragma unroll
    for (int t = 0; t < 2; ++t) {
        const int row = wv * 32 + t * 16 + lm;
        #pragma unroll
        for (int nt = 0; nt < 16; ++nt) {
            const int col = nt * 16 + lk * 4;
            const float4 bv = *(const float4*)(bias + col);
            float4 vv = make_float4(acc[t][nt][0] + bv.x, acc[t][nt][1] + bv.y,
                                    acc[t][nt][2] + bv.z, acc[t][nt][3] + bv.w);
            *(float4*)&ob[(size_t)row * 256 + col] = vv;
        }
    }
}

// ============================================================================
extern "C" void kernel_launch(void* const* d_in, const int* in_sizes, int n_in,
                              void* d_out, int out_size, void* d_ws, size_t ws_size,
                              hipStream_t stream)
{
    const float* x  = (const float*)d_in[0];
    const float* w1 = (const float*)d_in[1];
    const float* w2 = (const float*)d_in[2];
    const float* wo = (const float*)d_in[3];
    const float* wb = (const float*)d_in[4];
    float* out = (float*)d_out;

    unsigned short* y2 = (unsigned short*)d_ws;                    // 100,663,296 B
    unsigned short* zz = y2 + (size_t)B_ * C3_ * H_ * WP_;         // + 33,554,432 B
    unsigned short* wh = y2;                                       // overlays dead y2 (after attn)
    unsigned short* wl = y2 + 65536;

    conv_kernel<<<dim3(1024), dim3(256), 0, stream>>>(x, w1, w2, y2);
    attn_kernel<<<dim3(4096), dim3(256), 0, stream>>>(y2, zz);
    prep_w<<<dim3(64), dim3(256), 0, stream>>>(wo, wh, wl);
    proj_kernel<<<dim3(512), dim3(256), 0, stream>>>(zz, wh, wl, wb, out);
}

// Round 16
// 115.178 us; speedup vs baseline: 1.0550x; 1.0234x over previous
//
#include <hip/hip_runtime.h>
#include <stdint.h>

#define B_   32
#define DIM_ 16
#define H_   128
#define DM_  256
#define NH_  8
#define WP_  32     // DM/NH
#define C3_  384    // 3*NH*DIM

typedef short bf16x8 __attribute__((ext_vector_type(8)));
typedef float f32x4  __attribute__((ext_vector_type(4)));

__device__ __forceinline__ unsigned short f2bfu(float v) {
    unsigned int x = __float_as_uint(v);
    x += 0x7fffu + ((x >> 16) & 1u);   // RNE
    return (unsigned short)(x >> 16);
}
__device__ __forceinline__ unsigned cvtpk(float lo, float hi) {
    unsigned r;
    asm("v_cvt_pk_bf16_f32 %0, %1, %2" : "=v"(r) : "v"(lo), "v"(hi));
    return r;
}
// async global->LDS, 16B per lane; lds dest = wave-uniform base + lane*16
__device__ __forceinline__ void gl_lds16(const void* g, void* l) {
    __builtin_amdgcn_global_load_lds(
        (const __attribute__((address_space(1))) unsigned int*)g,
        (__attribute__((address_space(3))) unsigned int*)l, 16, 0, 0);
}
// issue two HW-transpose LDS reads WITHOUT waiting (batched-wait pattern):
// caller must s_waitcnt lgkmcnt(0) + sched_barrier(0) before consuming.
__device__ __forceinline__ void tr_pair(const void* p, uint2& r0, uint2& r1) {
    const __attribute__((address_space(3))) unsigned char* lp =
        (const __attribute__((address_space(3))) unsigned char*)p;
    asm volatile("ds_read_b64_tr_b16 %0, %2\n\t"
                 "ds_read_b64_tr_b16 %1, %2 offset:512"
                 : "=v"(r0), "=v"(r1) : "v"(lp) : "memory");
}
__device__ __forceinline__ bf16x8 mk8(uint2 r0, uint2 r1) {
    union { uint4 u; bf16x8 v; } c;
    c.u = make_uint4(r0.x, r0.y, r1.x, r1.y);
    return c.v;
}

// ============================================================================
// Kernel 1 (v12): v9 pure-store conv with FULL-CACHE-LINE wave stores.
// Unchanged from round 15 (passed; conv ~50us, best conv measured).
// hl = tid&7, wp = tid>>3 -> each wave's uint4 store covers 8 full 128B lines.
// Layout [o][wp][h] for ALL channels.
// Grid: 32 b * 16 g * 2 ht = 1024 blocks, 256 thr.
// ============================================================================
__global__ __launch_bounds__(256) void conv_kernel(
    const float* __restrict__ x, const float* __restrict__ w1,
    const float* __restrict__ w2, unsigned short* __restrict__ y2)
{
    __shared__ float wlds[24 * 16];   // [oc][0..4]=w1, [5..12]=w2, rest pad

    const int bid = blockIdx.x;
    const int ht = bid & 1;
    const int g  = (bid >> 1) & 15;
    const int b  = bid >> 5;
    const int tid = threadIdx.x;
    const int hl = tid & 7;           // h-oct within half (minor -> contiguity)
    const int wp = tid >> 3;          // 0..31
    const int h0 = ht * 64 + hl * 8;  // first output h of this thread

    for (int i = tid; i < 384; i += 256) {
        const int oc = i >> 4, ix = i & 15;
        const int o = g * 24 + oc;
        float v = 0.f;
        if (ix < 5)       v = w1[o * 5 + ix];
        else if (ix < 13) v = w2[o * 8 + (ix - 5)];
        wlds[i] = v;
    }

    const float* xbase = x + ((size_t)(b * DIM_ + g) * H_) * DM_ + wp * 8;

    float xr[12][8];
    #pragma unroll
    for (int r = 0; r < 12; ++r) {
        const int hr = h0 - 2 + r;
        if (hr >= 0 && hr < H_) {
            const float4* p = (const float4*)(xbase + (size_t)hr * DM_);
            float4 a = p[0], c = p[1];
            xr[r][0] = a.x; xr[r][1] = a.y; xr[r][2] = a.z; xr[r][3] = a.w;
            xr[r][4] = c.x; xr[r][5] = c.y; xr[r][6] = c.z; xr[r][7] = c.w;
        } else {
            #pragma unroll
            for (int j = 0; j < 8; ++j) xr[r][j] = 0.f;
        }
    }
    __syncthreads();

    // store base: [o][wp][h], o = g*24 + oc
    unsigned short* yb = y2 + ((size_t)(b * C3_ + g * 24) * 32 + wp) * 128 + h0;

    for (int oc = 0; oc < 24; ++oc) {
        const float* wo_ = &wlds[oc * 16];
        float w1r[5], w2r[8];
        {
            float4 a = *(const float4*)(wo_);       // w1[0..3]
            float4 c = *(const float4*)(wo_ + 4);   // w1[4], w2[0..2]
            float4 d = *(const float4*)(wo_ + 8);   // w2[3..6]
            w1r[0] = a.x; w1r[1] = a.y; w1r[2] = a.z; w1r[3] = a.w;
            w1r[4] = c.x;
            w2r[0] = c.y; w2r[1] = c.z; w2r[2] = c.w;
            w2r[3] = d.x; w2r[4] = d.y; w2r[5] = d.z; w2r[6] = d.w;
            w2r[7] = wo_[12];
        }

        float u[12];
        #pragma unroll
        for (int r = 0; r < 12; ++r) {
            float s = w2r[0] * xr[r][0];
            #pragma unroll
            for (int j = 1; j < 8; ++j) s = fmaf(w2r[j], xr[r][j], s);
            u[r] = s;
        }

        float ys[8];
        #pragma unroll
        for (int hh = 0; hh < 8; ++hh) {
            float y = w1r[0] * u[hh];
            #pragma unroll
            for (int t = 1; t < 5; ++t) y = fmaf(w1r[t], u[hh + t], y);
            ys[hh] = y;
        }
        uint4 pk;
        pk.x = cvtpk(ys[0], ys[1]); pk.y = cvtpk(ys[2], ys[3]);
        pk.z = cvtpk(ys[4], ys[5]); pk.w = cvtpk(ys[6], ys[7]);
        *(uint4*)(yb + (size_t)oc * 4096) = pk;
    }
}

// ============================================================================
// Kernel 2 (v4): MFMA attention per (b, ch), [o][d][h] input.
// Identical layouts/formulas to round-15 (passed); ONLY change: the 20
// ds_read_b64_tr_b16 are issued back-to-back and drained with a SINGLE
// s_waitcnt lgkmcnt(0) + sched_barrier(0) (was 10x {drain,2 reads,drain} --
// ~20 exposed LDS latencies serialized per wave -> the ~39us attn).
// ============================================================================
__global__ __launch_bounds__(256) void attn_kernel(
    const unsigned short* __restrict__ y2, unsigned short* __restrict__ z)
{
    __shared__ __align__(16) unsigned char sm[40960];

    const int tid = threadIdx.x;
    const int ch = blockIdx.x & 127, b = blockIdx.x >> 7;
    const size_t base = ((size_t)(b * C3_ + ch)) * 4096;
    const uint4* qg = (const uint4*)(y2 + base);
    const uint4* kg = (const uint4*)(y2 + base + 128 * 4096);
    const uint4* vg = (const uint4*)(y2 + base + 256 * 4096);

    // ---- stage: Q tiles @0, K tiles @8192 (tr-tile layout), Vt @32768 ----
    #pragma unroll
    for (int r = 0; r < 2; ++r) {
        const int ci  = tid + r * 256;   // 0..511 uint4 chunks: [d=ci>>4][hc=ci&15]
        const int vd  = ci >> 4;         // 0..31
        const int vhc = ci & 15;         // 16B chunk along h (8 h values)
        const int toff = (vhc >> 1) * 1024 +
            ((((vhc & 1) * 8) + 16 * (vd & 3) + 256 * ((vd >> 2) & 1) + 64 * (vd >> 3)) << 1);
        *(uint4*)(sm + toff)        = qg[ci];
        *(uint4*)(sm + 8192 + toff) = kg[ci];
        *(uint4*)(sm + 32768 + vd * 256 + ((vhc * 16) ^ ((vd & 7) << 4))) = vg[ci];
    }
    __syncthreads();

    const int l  = tid & 63, wv = tid >> 6;
    const int lm = l & 15,  lk = l >> 4;
    const unsigned rdo = ((l & 15) + 64 * (l >> 4)) * 2;   // tr-read offset

    // ---- QK^T: issue ALL transpose reads, single wait, then pure-reg MFMAs ----
    uint2 qr0[2], qr1[2], kr0[8], kr1[8];
    #pragma unroll
    for (int t = 0; t < 2; ++t)
        tr_pair(sm + (wv * 2 + t) * 1024 + rdo, qr0[t], qr1[t]);
    #pragma unroll
    for (int rt = 0; rt < 8; ++rt)
        tr_pair(sm + 8192 + rt * 1024 + rdo, kr0[rt], kr1[rt]);
    asm volatile("s_waitcnt lgkmcnt(0)" ::: "memory");
    __builtin_amdgcn_sched_barrier(0);

    bf16x8 qf[2];
    qf[0] = mk8(qr0[0], qr1[0]);
    qf[1] = mk8(qr0[1], qr1[1]);

    f32x4 acc[8][2];
    #pragma unroll
    for (int rt = 0; rt < 8; ++rt) {
        acc[rt][0] = 0; acc[rt][1] = 0;
    }
    #pragma unroll
    for (int rt = 0; rt < 8; ++rt) {
        bf16x8 kf = mk8(kr0[rt], kr1[rt]);
        acc[rt][0] = __builtin_amdgcn_mfma_f32_16x16x32_bf16(kf, qf[0], acc[rt][0], 0, 0, 0);
        acc[rt][1] = __builtin_amdgcn_mfma_f32_16x16x32_bf16(kf, qf[1], acc[rt][1], 0, 0, 0);
    }

    const float Cc = 0.17677669529663687f * 1.4426950408889634f;
    float inv[2];
    #pragma unroll
    for (int t = 0; t < 2; ++t) {
        float m = acc[0][t][0];
        #pragma unroll
        for (int rt = 0; rt < 8; ++rt)
            #pragma unroll
            for (int rg = 0; rg < 4; ++rg) m = fmaxf(m, acc[rt][t][rg]);
        m = fmaxf(m, __shfl_xor(m, 16));
        m = fmaxf(m, __shfl_xor(m, 32));
        float s = 0.f;
        #pragma unroll
        for (int rt = 0; rt < 8; ++rt)
            #pragma unroll
            for (int rg = 0; rg < 4; ++rg) {
                float p = exp2f((acc[rt][t][rg] - m) * Cc);
                acc[rt][t][rg] = p; s += p;
            }
        s += __shfl_xor(s, 16);
        s += __shfl_xor(s, 32);
        inv[t] = 1.0f / s;
    }

    __syncthreads();   // Q/K reads done -> safe to overlay P

    #pragma unroll
    for (int t = 0; t < 2; ++t) {
        const int q = (wv * 2 + t) * 16 + lm;
        #pragma unroll
        for (int rt = 0; rt < 8; ++rt) {
            unsigned u0 = cvtpk(acc[rt][t][0] * inv[t], acc[rt][t][1] * inv[t]);
            unsigned u1 = cvtpk(acc[rt][t][2] * inv[t], acc[rt][t][3] * inv[t]);
            const int kb = rt * 32 + lk * 8;
            *(uint2*)(sm + q * 256 + (kb ^ ((q & 7) << 4))) = make_uint2(u0, u1);
        }
    }
    __syncthreads();

    f32x4 o[2][2];
    o[0][0] = 0; o[0][1] = 0; o[1][0] = 0; o[1][1] = 0;
    #pragma unroll
    for (int kc = 0; kc < 4; ++kc) {
        const int cb = kc * 64 + lk * 16;
        bf16x8 av[2], bp[2];
        #pragma unroll
        for (int dt = 0; dt < 2; ++dt) {
            const int d = dt * 16 + lm;
            av[dt] = *(const bf16x8*)(sm + 32768 + d * 256 + (cb ^ ((d & 7) << 4)));
        }
        #pragma unroll
        for (int t = 0; t < 2; ++t) {
            const int q = (wv * 2 + t) * 16 + lm;
            bp[t] = *(const bf16x8*)(sm + q * 256 + (cb ^ ((q & 7) << 4)));
        }
        #pragma unroll
        for (int dt = 0; dt < 2; ++dt)
            #pragma unroll
            for (int t = 0; t < 2; ++t)
                o[dt][t] = __builtin_amdgcn_mfma_f32_16x16x32_bf16(av[dt], bp[t], o[dt][t], 0, 0, 0);
    }

    const int dd = ch >> 3, nn = ch & 7;
    unsigned short* zb = z + ((size_t)(b * DIM_ + dd)) * (H_ * DM_);
    #pragma unroll
    for (int dt = 0; dt < 2; ++dt)
        #pragma unroll
        for (int t = 0; t < 2; ++t) {
            const int q  = (wv * 2 + t) * 16 + lm;
            const int d0 = dt * 16 + lk * 4;
            unsigned u0 = cvtpk(o[dt][t][0], o[dt][t][1]);
            unsigned u1 = cvtpk(o[dt][t][2], o[dt][t][3]);
            *(uint2*)(zb + (size_t)q * DM_ + nn * 32 + d0) = make_uint2(u0, u1);
        }
}

// ============================================================================
// Kernel 3: W -> bf16 hi/lo split. Unchanged.
// ============================================================================
__global__ __launch_bounds__(256) void prep_w(
    const float* __restrict__ w, unsigned short* __restrict__ wh,
    unsigned short* __restrict__ wl)
{
    const int i = blockIdx.x * 1024 + threadIdx.x * 4;
    float4 v = *(const float4*)(w + i);
    float vv[4] = { v.x, v.y, v.z, v.w };
    unsigned short h[4], lo[4];
    #pragma unroll
    for (int j = 0; j < 4; ++j) {
        h[j] = f2bfu(vv[j]);
        float hf = __uint_as_float(((unsigned)h[j]) << 16);
        lo[j] = f2bfu(vv[j] - hf);
    }
    *(uint2*)(wh + i) = make_uint2((unsigned)h[0] | ((unsigned)h[1] << 16),
                                   (unsigned)h[2] | ((unsigned)h[3] << 16));
    *(uint2*)(wl + i) = make_uint2((unsigned)lo[0] | ((unsigned)lo[1] << 16),
                                   (unsigned)lo[2] | ((unsigned)lo[3] << 16));
}

// ============================================================================
// Kernel 4 (v2): MFMA out-projection, swapped operands + float4 epilogue.
// Unchanged (known-good).
// ============================================================================
__global__ __launch_bounds__(256) void proj_kernel(
    const unsigned short* __restrict__ zz, const unsigned short* __restrict__ wh,
    const unsigned short* __restrict__ wl, const float* __restrict__ bias,
    float* __restrict__ out)
{
    __shared__ __align__(16) unsigned char sm[65536];   // 2 bufs x 32KB
    const int tid = threadIdx.x;
    const int l = tid & 63, wv = tid >> 6, lm = l & 15, lk = l >> 4;
    const unsigned short* zs = zz + (size_t)blockIdx.x * 32768;

    const int g_off = (tid >> 2) * 256 + (tid & 3) * 8;
    const int lds_wv = wv * 1024;

    const int arow0 = wv * 32 + lm;

    f32x4 acc[2][16];
    #pragma unroll
    for (int t = 0; t < 2; ++t)
        #pragma unroll
        for (int nt = 0; nt < 16; ++nt) acc[t][nt] = 0;

    bf16x8 areg[2][2];

    #pragma unroll
    for (int i = 0; i < 8; ++i) {
        const unsigned short* g = (i < 4 ? wh : wl) + g_off + (i & 3) * 16384;
        gl_lds16(g, sm + i * 4096 + lds_wv);
    }
    #pragma unroll
    for (int t = 0; t < 2; ++t)
        areg[0][t] = *(const bf16x8*)(zs + (size_t)(arow0 + t * 16) * 256 + lk * 8);

    __syncthreads();

    #pragma unroll
    for (int kc = 0; kc < 8; ++kc) {
        const int buf = kc & 1;
        if (kc < 7) {
            #pragma unroll
            for (int i = 0; i < 8; ++i) {
                const unsigned short* g = (i < 4 ? wh : wl) + g_off + (i & 3) * 16384 + (kc + 1) * 32;
                gl_lds16(g, sm + (buf ^ 1) * 32768 + i * 4096 + lds_wv);
            }
            #pragma unroll
            for (int t = 0; t < 2; ++t)
                areg[buf ^ 1][t] = *(const bf16x8*)(zs + (size_t)(arow0 + t * 16) * 256 + (kc + 1) * 32 + lk * 8);
        }
        #pragma unroll
        for (int ph = 0; ph < 2; ++ph)
            #pragma unroll
            for (int nt = 0; nt < 16; ++nt) {
                bf16x8 bf = *(const bf16x8*)(sm + buf * 32768 + ph * 16384 + nt * 1024 + lm * 64 + lk * 16);
                acc[0][nt] = __builtin_amdgcn_mfma_f32_16x16x32_bf16(bf, areg[buf][0], acc[0][nt], 0, 0, 0);
                acc[1][nt] = __builtin_amdgcn_mfma_f32_16x16x32_bf16(bf, areg[buf][1], acc[1][nt], 0, 0, 0);
            }
        __syncthreads();
    }

    float* ob = out + (size_t)blockIdx.x * 32768;
    #pragma unroll
    for (int t = 0; t < 2; ++t) {
        const int row = wv * 32 + t * 16 + lm;
        #pragma unroll
        for (int nt = 0; nt < 16; ++nt) {
            const int col = nt * 16 + lk * 4;
            const float4 bv = *(const float4*)(bias + col);
            float4 vv = make_float4(acc[t][nt][0] + bv.x, acc[t][nt][1] + bv.y,
                                    acc[t][nt][2] + bv.z, acc[t][nt][3] + bv.w);
            *(float4*)&ob[(size_t)row * 256 + col] = vv;
        }
    }
}

// ============================================================================
extern "C" void kernel_launch(void* const* d_in, const int* in_sizes, int n_in,
                              void* d_out, int out_size, void* d_ws, size_t ws_size,
                              hipStream_t stream)
{
    const float* x  = (const float*)d_in[0];
    const float* w1 = (const float*)d_in[1];
    const float* w2 = (const float*)d_in[2];
    const float* wo = (const float*)d_in[3];
    const float* wb = (const float*)d_in[4];
    float* out = (float*)d_out;

    unsigned short* y2 = (unsigned short*)d_ws;                    // 100,663,296 B
    unsigned short* zz = y2 + (size_t)B_ * C3_ * H_ * WP_;         // + 33,554,432 B
    unsigned short* wh = y2;                                       // overlays dead y2 (after attn)
    unsigned short* wl = y2 + 65536;

    conv_kernel<<<dim3(1024), dim3(256), 0, stream>>>(x, w1, w2, y2);
    attn_kernel<<<dim3(4096), dim3(256), 0, stream>>>(y2, zz);
    prep_w<<<dim3(64), dim3(256), 0, stream>>>(wo, wh, wl);
    proj_kernel<<<dim3(512), dim3(256), 0, stream>>>(zz, wh, wl, wb, out);
}